// Round 5
// baseline (277.579 us; speedup 1.0000x reference)
//
#include <hip/hip_runtime.h>
#include <cstdint>

#define NTOT 242991
#define BATCH 8
#define KTOT 8741           // 2000*4 + 741
#define CAP 8192            // candidate buffer per (b,level)
#define NBIN 4096           // histogram bins (top 12 ordered bits)
#define CSTR 16             // counter padding stride
#define MEMTOT 1943928      // sum over levels of B*3*H*W  (== BATCH*NTOT)
#define ANCTOT (BATCH * NTOT)
#define SCAP 4096           // k_scan chunk capacity
#define SLICE 256           // suppression-matrix slice

__device__ __forceinline__ int level_of(int n) {
    if (n < 182400) return 0;
    if (n < 228000) return 1;
    if (n < 239400) return 2;
    if (n < 242250) return 3;
    return 4;
}

__device__ __forceinline__ void locate(int n, int& l, int& H, int& W, int& loc) {
    if (n < 182400)      { l = 0; H = 200; W = 304; loc = n; }
    else if (n < 228000) { l = 1; H = 100; W = 152; loc = n - 182400; }
    else if (n < 239400) { l = 2; H = 50;  W = 76;  loc = n - 228000; }
    else if (n < 242250) { l = 3; H = 25;  W = 38;  loc = n - 239400; }
    else                 { l = 4; H = 13;  W = 19;  loc = n - 242250; }
}

// classify mem-flat cls index -> bl = b*5+l
__device__ __forceinline__ int classify_bl(int x) {
    int l, HW;
    if (x < 1459200)      { l = 0; HW = 60800; }
    else if (x < 1824000) { l = 1; HW = 15200; x -= 1459200; }
    else if (x < 1915200) { l = 2; HW = 3800;  x -= 1824000; }
    else if (x < 1938000) { l = 3; HW = 950;   x -= 1915200; }
    else                  { l = 4; HW = 247;   x -= 1938000; }
    return (x / (3 * HW)) * 5 + l;
}

// block-wide (1024 thr) inclusive SUFFIX scan; 2 barriers
__device__ __forceinline__ uint32_t suffix_scan_1024(uint32_t g, uint32_t* lds16, int t) {
    int lane = t & 63, wid = t >> 6;
    uint32_t v = g;
#pragma unroll
    for (int o = 1; o < 64; o <<= 1) {
        uint32_t oth = __shfl_down(v, o, 64);
        if (lane + o < 64) v += oth;
    }
    if (lane == 0) lds16[wid] = v;      // wave total
    __syncthreads();
    uint32_t w = 0;
    for (int q = wid + 1; q < 16; q++) w += lds16[q];
    __syncthreads();
    return v + w;                        // inclusive suffix over block
}

// ---- kernel 1: scores -> ordered keys (anchor order) + per-(b,l) hist ----
__global__ __launch_bounds__(1024)
void k_keys(const float* __restrict__ c0, const float* __restrict__ c1,
            const float* __restrict__ c2, const float* __restrict__ c3,
            const float* __restrict__ c4,
            uint32_t* __restrict__ keys32, uint32_t* __restrict__ hist) {
    int t = threadIdx.x;
    int base = blockIdx.x * 1024;
    int gid = base + t;
    bool in = gid < MEMTOT;
    __shared__ uint32_t lh[NBIN];

    int bl = 0;
    uint32_t u = 0;
    if (in) {
        int x = gid;
        const float* cp; int HW, off, l;
        if (x < 1459200)      { l = 0; cp = c0; HW = 60800; off = 0; }
        else if (x < 1824000) { l = 1; cp = c1; HW = 15200; off = 182400; x -= 1459200; }
        else if (x < 1915200) { l = 2; cp = c2; HW = 3800;  off = 228000; x -= 1824000; }
        else if (x < 1938000) { l = 3; cp = c3; HW = 950;   off = 239400; x -= 1915200; }
        else                  { l = 4; cp = c4; HW = 247;   off = 242250; x -= 1938000; }
        int seg = 3 * HW;
        int b = x / seg, r = x - b * seg;
        int a = r / HW, pix = r - a * HW;
        int n = off + pix * 3 + a;
        float sv = cp[x];
        u = __float_as_uint(sv);
        u ^= (u >> 31) ? 0xFFFFFFFFu : 0x80000000u;    // monotonic float->uint
        keys32[(size_t)b * NTOT + n] = u;
        bl = b * 5 + l;
    }
    int blf = classify_bl(base);
    int bll = classify_bl(min(base + 1023, MEMTOT - 1));
    if (blf == bll) {
        for (int j = t; j < NBIN; j += 1024) lh[j] = 0u;
        __syncthreads();
        if (in) atomicAdd(&lh[u >> 20], 1u);
        __syncthreads();
        uint32_t* gh = hist + (size_t)blf * NBIN;
        for (int j = t; j < NBIN; j += 1024) {
            uint32_t v = lh[j];
            if (v) atomicAdd(&gh[j], v);
        }
    } else {
        if (in) atomicAdd(&hist[(size_t)bl * NBIN + (u >> 20)], 1u);
    }
}

// ---- kernel 2: per-(b,l) threshold bin + remainder (parallel scan) ----
__global__ void k_bins(const uint32_t* __restrict__ hist, int* __restrict__ binT,
                       int* __restrict__ rrem) {
    int bl = blockIdx.x;             // 40 blocks
    const uint32_t* h = hist + (size_t)bl * NBIN;
    int l = bl % 5;
    uint32_t k = (l == 4) ? 741u : 2000u;
    __shared__ uint32_t ts[256];
    __shared__ uint32_t sb[256];
    int t = threadIdx.x;             // 256 threads, 16 bins each
    uint32_t s = 0;
    for (int i = 0; i < 16; i++) s += h[t * 16 + i];
    ts[t] = s; sb[t] = s;
    __syncthreads();
    for (int d = 1; d < 256; d <<= 1) {
        uint32_t add = (t + d < 256) ? sb[t + d] : 0u;
        __syncthreads();
        sb[t] += add;
        __syncthreads();
    }
    uint32_t inc = sb[t], excl = inc - ts[t];   // suffix strictly above this group
    if (excl < k && inc >= k) {
        uint32_t cum = excl;
        for (int bin = t * 16 + 15; bin >= t * 16; bin--) {
            uint32_t hh = h[bin];
            if (cum + hh >= k) { binT[bl] = bin; rrem[bl] = (int)(k - cum); break; }
            cum += hh;
        }
    }
}

// ---- kernel 3: wide compact (wave-aggregated, uniformity-checked) ----
__global__ __launch_bounds__(1024)
void k_compact(const uint32_t* __restrict__ keys32, const int* __restrict__ binT,
               uint32_t* __restrict__ keep, uint32_t* __restrict__ keep_cnt,
               uint32_t* __restrict__ cand, uint32_t* __restrict__ cand_cnt) {
    int gid = blockIdx.x * 1024 + threadIdx.x;
    bool in = gid < ANCTOT;
    int b = 0, n = 0, l = 0;
    uint32_t u = 0;
    if (in) {
        b = gid / NTOT; n = gid - b * NTOT;
        l = level_of(n);
        u = keys32[gid];
    }
    int bl = b * 5 + l;
    int T = in ? binT[bl] : 0x7FFFFFFF;
    int bin = (int)(u >> 20);
    bool pk = in && (bin > T);
    bool pc = in && (bin == T);
    int lane = threadIdx.x & 63;

    unsigned long long act = __ballot(in);
    if (act == 0ull) return;
    int lead = __ffsll(act) - 1;
    int bl0 = __shfl(bl, lead, 64);
    bool unif = (__ballot(in && (bl == bl0)) == act);
    if (unif) {
        int b0 = bl0 / 5, l0 = bl0 % 5;
        uint32_t kbase = (uint32_t)(b0 * KTOT + l0 * 2000);
        unsigned long long mk = __ballot(pk);
        if (mk) {
            int leader = __ffsll(mk) - 1;
            uint32_t bs = 0;
            if (lane == leader) bs = atomicAdd(&keep_cnt[bl0 * CSTR], (uint32_t)__popcll(mk));
            bs = __shfl(bs, leader, 64);
            if (pk) {
                int pos = __popcll(mk & ((1ull << lane) - 1ull));
                keep[kbase + bs + (uint32_t)pos] = (uint32_t)n;
            }
        }
        unsigned long long mc = __ballot(pc);
        if (mc) {
            int leader = __ffsll(mc) - 1;
            uint32_t bs = 0;
            if (lane == leader) bs = atomicAdd(&cand_cnt[bl0 * CSTR], (uint32_t)__popcll(mc));
            bs = __shfl(bs, leader, 64);
            if (pc) {
                int pos = __popcll(mc & ((1ull << lane) - 1ull));
                uint32_t p = bs + (uint32_t)pos;
                if (p < CAP) cand[(size_t)bl0 * CAP + p] = (uint32_t)n;
            }
        }
    } else {  // rare straddle waves: scalar atomics
        if (pk) {
            uint32_t p = atomicAdd(&keep_cnt[bl * CSTR], 1u);
            keep[b * KTOT + l * 2000 + p] = (uint32_t)n;
        }
        if (pc) {
            uint32_t p = atomicAdd(&cand_cnt[bl * CSTR], 1u);
            if (p < CAP) cand[(size_t)bl * CAP + p] = (uint32_t)n;
        }
    }
}

// ---- kernel 4: exact radix select over boundary candidates (52-bit, 5 passes) ----
__global__ __launch_bounds__(1024)
void k_select(const uint32_t* __restrict__ keys32, const uint32_t* __restrict__ cand,
              const uint32_t* __restrict__ cand_cnt, const int* __restrict__ rrem,
              uint32_t* __restrict__ keep, uint32_t* __restrict__ keep_cnt) {
    int bl = blockIdx.x;             // 40 blocks x 1024 threads
    int b = bl / 5, l = bl % 5;
    int C = (int)min(cand_cnt[bl * CSTR], (uint32_t)CAP);
    int r = rrem[bl];
    const uint32_t* cd = cand + (size_t)bl * CAP;
    const uint32_t* kp = keys32 + (size_t)b * NTOT;
    __shared__ uint32_t hist_l[2048];
    __shared__ uint32_t lds16[16];
    __shared__ unsigned long long pref_sh;
    __shared__ uint32_t kk_sh;
    int t = threadIdx.x;
    if (t == 0) { pref_sh = 0ull; kk_sh = (uint32_t)r; }
    unsigned long long maskAcc = 0ull;
    const int shifts[5] = {41, 30, 19, 8, 0};
    const uint32_t masks[5] = {0x7FFu, 0x7FFu, 0x7FFu, 0x7FFu, 0xFFu};
    __syncthreads();
    for (int p = 0; p < 5; p++) {
        int shift = shifts[p];
        uint32_t msk = masks[p];
        for (int j = t; j < 2048; j += 1024) hist_l[j] = 0u;
        __syncthreads();
        unsigned long long pref = pref_sh;
        uint32_t kk = kk_sh;
        for (int i = t; i < C; i += 1024) {
            uint32_t n = cd[i];
            unsigned long long key =
                ((unsigned long long)kp[n] << 32) | (uint32_t)(~n);
            if ((key & maskAcc) == pref)
                atomicAdd(&hist_l[(uint32_t)(key >> shift) & msk], 1u);
        }
        __syncthreads();
        uint32_t g = hist_l[2 * t] + hist_l[2 * t + 1];
        uint32_t inc = suffix_scan_1024(g, lds16, t);
        uint32_t excl = inc - g;
        if (excl < kk && inc >= kk) {       // unique crossing thread
            uint32_t hh1 = hist_l[2 * t + 1];
            uint32_t digit, rem;
            if (excl + hh1 >= kk) { digit = 2 * t + 1; rem = kk - excl; }
            else { digit = 2 * t; rem = kk - (excl + hh1); }
            pref_sh = pref | ((unsigned long long)digit << shift);
            kk_sh = rem;
        }
        __syncthreads();
        maskAcc |= (unsigned long long)msk << shift;
    }
    unsigned long long Tk = pref_sh;
    __syncthreads();
    int lane = t & 63;
    for (int i0 = 0; i0 < C; i0 += 1024) {
        int i = i0 + t;
        bool in = i < C;
        uint32_t n = in ? cd[i] : 0u;
        unsigned long long key = in ?
            (((unsigned long long)kp[n] << 32) | (uint32_t)(~n)) : 0ull;
        bool pr = in && ((key & maskAcc) >= Tk);
        unsigned long long mk = __ballot(pr);
        if (mk) {
            int leader = __ffsll(mk) - 1;
            uint32_t bs = 0;
            if (lane == leader) bs = atomicAdd(&keep_cnt[bl * CSTR], (uint32_t)__popcll(mk));
            bs = __shfl(bs, leader, 64);
            if (pr) {
                int pos = __popcll(mk & ((1ull << lane) - 1ull));
                keep[(size_t)b * KTOT + l * 2000 + bs + (uint32_t)pos] = n;
            }
        }
    }
}

// ---- kernel 5: decode + clip + validity + bucket histogram ----
__global__ void k_decode(const float* __restrict__ b0, const float* __restrict__ b1,
                         const float* __restrict__ b2, const float* __restrict__ b3,
                         const float* __restrict__ b4, const float* __restrict__ anchors,
                         const uint32_t* __restrict__ keys32, const uint32_t* __restrict__ keep,
                         float4* __restrict__ nbox, unsigned long long* __restrict__ nkey,
                         uint32_t* __restrict__ shist) {
    int gid = blockIdx.x * blockDim.x + threadIdx.x;
    if (gid >= BATCH * KTOT) return;
    int b = gid / KTOT;
    int n = (int)keep[gid];
    int l, H, W, loc; locate(n, l, H, W, loc);
    int a = loc % 3, hw = loc / 3;
    int w = hw % W, h = hw / W;
    const float* bp = (l == 0) ? b0 : (l == 1) ? b1 : (l == 2) ? b2 : (l == 3) ? b3 : b4;
    int HW = H * W;
    int base = ((b * 12 + a * 4) * H + h) * W + w;
    float dx = bp[base], dy = bp[base + HW];
    float dw = bp[base + 2 * HW], dh = bp[base + 3 * HW];
    float ax1 = anchors[4 * n], ay1 = anchors[4 * n + 1];
    float ax2 = anchors[4 * n + 2], ay2 = anchors[4 * n + 3];
    float wa = ax2 - ax1, ha = ay2 - ay1;
    float cxa = ax1 + 0.5f * wa, cya = ay1 + 0.5f * ha;
    const float CLIPV = 4.135166556742356f;    // log(1000/16)
    dw = fminf(dw, CLIPV); dh = fminf(dh, CLIPV);
    float cx = dx * wa + cxa, cy = dy * ha + cya;
    float pw = expf(dw) * wa, ph = expf(dh) * ha;
    float x1 = cx - 0.5f * pw, y1 = cy - 0.5f * ph;
    float x2 = cx + 0.5f * pw, y2 = cy + 0.5f * ph;
    x1 = fminf(fmaxf(x1, 0.f), 1216.f); x2 = fminf(fmaxf(x2, 0.f), 1216.f);
    y1 = fminf(fmaxf(y1, 0.f), 800.f);  y2 = fminf(fmaxf(y2, 0.f), 800.f);
    bool valid = ((x2 - x1) >= 1e-3f) && ((y2 - y1) >= 1e-3f);
    uint32_t o = keys32[(size_t)b * NTOT + n];
    float off = (float)l * 1217.0f;            // max(IMG_H,IMG_W)+1
    nbox[gid] = make_float4(x1 + off, y1 + off, x2 + off, y2 + off);
    nkey[gid] = valid ? (((unsigned long long)o << 32) | (uint32_t)(~n)) : 0ull;
    if (valid) atomicAdd(&shist[b * NBIN + (o >> 20)], 1u);
}

// ---- kernel 6: chunked rank-sort + suppression-matrix NMS, 1 block/image ----
__global__ __launch_bounds__(1024)
void k_scan(const unsigned long long* __restrict__ nkey, const float4* __restrict__ nbox,
            const uint32_t* __restrict__ shist, float* __restrict__ out) {
    int b = blockIdx.x, t = threadIdx.x, lane = t & 63, wid = t >> 6;
    const unsigned long long* K = nkey + (size_t)b * KTOT;
    const float4* BX = nbox + (size_t)b * KTOT;

    __shared__ unsigned long long k_l[SCAP];        // 32 KB keys (gather->sorted)
    __shared__ unsigned short p_l[SCAP];            // 8 KB payload
    __shared__ float4 box_l[SLICE];                 // 4 KB slice boxes
    __shared__ uint32_t rows[SLICE * (SLICE / 32)]; // 8 KB suppression matrix
    __shared__ float4 sel_l[100];                   // 1.6 KB selected boxes
    __shared__ unsigned char chunk_of[NBIN];        // 4 KB
    __shared__ uint32_t sup[SLICE / 32];
    __shared__ uint32_t lds16[16];
    __shared__ uint32_t cnt_sh, picks_sh;
    __shared__ unsigned long long gmax_sh;
    __shared__ uint32_t jpos_sh;
    __shared__ unsigned long long wred[16];

    // ---- phase A: bucket suffix-cumulative -> 512-granular chunk ids ----
    uint32_t* hist_l = (uint32_t*)k_l;              // 16 KB overlay
    for (int j = t; j < NBIN; j += 1024) hist_l[j] = shist[b * NBIN + j];
    if (t == 0) picks_sh = 0u;
    __syncthreads();
    uint32_t h0 = hist_l[4 * t], h1 = hist_l[4 * t + 1],
             h2 = hist_l[4 * t + 2], h3 = hist_l[4 * t + 3];
    uint32_t g = h0 + h1 + h2 + h3;
    uint32_t inc = suffix_scan_1024(g, lds16, t);
    uint32_t acc = inc - g;                         // suffix strictly above group
    chunk_of[4 * t + 3] = (unsigned char)min(acc >> 9, 255u); acc += h3;
    chunk_of[4 * t + 2] = (unsigned char)min(acc >> 9, 255u); acc += h2;
    chunk_of[4 * t + 1] = (unsigned char)min(acc >> 9, 255u); acc += h1;
    chunk_of[4 * t + 0] = (unsigned char)min(acc >> 9, 255u);
    __syncthreads();

    uint32_t picks = 0;
    for (int m = 0; m < 18 && picks < 100u; m++) {
        if (t == 0) cnt_sh = 0u;
        __syncthreads();
        // gather chunk m
        for (int j0 = 0; j0 < KTOT; j0 += 1024) {
            int j = j0 + t;
            unsigned long long kk = 0ull;
            bool take = false;
            if (j < KTOT) {
                kk = K[j];
                take = (kk != 0ull) && (chunk_of[(uint32_t)(kk >> 52)] == (unsigned char)m);
            }
            unsigned long long msk = __ballot(take);
            if (msk) {
                int leader = __ffsll(msk) - 1;
                uint32_t bs = 0;
                if (lane == leader) bs = atomicAdd(&cnt_sh, (uint32_t)__popcll(msk));
                bs = __shfl(bs, leader, 64);
                if (take) {
                    uint32_t pos = bs + (uint32_t)__popcll(msk & ((1ull << lane) - 1ull));
                    if (pos < SCAP) { k_l[pos] = kk; p_l[pos] = (unsigned short)j; }
                }
            }
        }
        __syncthreads();
        uint32_t cnt = cnt_sh;
        if (cnt == 0u) continue;

        if (cnt <= SCAP) {
            // ---- rank sort (all-pairs broadcast compare), in place ----
            unsigned long long myk[4]; unsigned short myp[4]; uint32_t myr[4];
            int nown = 0;
            for (uint32_t i = t; i < cnt; i += 1024) {
                myk[nown] = k_l[i]; myp[nown] = p_l[i]; myr[nown] = 0u; nown++;
            }
            for (uint32_t j = 0; j < cnt; j++) {
                unsigned long long kj = k_l[j];
                for (int e = 0; e < nown; e++) if (kj > myk[e]) myr[e]++;
            }
            __syncthreads();
            for (int e = 0; e < nown; e++) { k_l[myr[e]] = myk[e]; p_l[myr[e]] = myp[e]; }
            __syncthreads();

            // ---- slices of 256 with precomputed suppression matrix ----
            for (uint32_t s0 = 0; s0 < cnt && picks < 100u; s0 += SLICE) {
                uint32_t sl = min((uint32_t)SLICE, cnt - s0);
                if (t < (int)sl) box_l[t] = BX[p_l[s0 + t]];
                if (t < SLICE / 32) sup[t] = 0u;
                __syncthreads();
                // pre-suppression vs already-selected boxes
                if (picks > 0u && t < (int)sl) {
                    float4 cb = box_l[t];
                    float ca = (cb.z - cb.x) * (cb.w - cb.y);
                    bool hit = false;
                    for (uint32_t s = 0; s < picks; s++) {
                        float4 sv = sel_l[s];
                        float xx1 = fmaxf(cb.x, sv.x), yy1 = fmaxf(cb.y, sv.y);
                        float xx2 = fminf(cb.z, sv.z), yy2 = fminf(cb.w, sv.w);
                        float inter = fmaxf(xx2 - xx1, 0.f) * fmaxf(yy2 - yy1, 0.f);
                        float sa = (sv.z - sv.x) * (sv.w - sv.y);
                        float un = ca + sa - inter;
                        if (un > 0.f && inter / un > 0.7f) { hit = true; break; }
                    }
                    if (hit) atomicOr(&sup[t >> 5], 1u << (t & 31));
                }
                // build suppression matrix: rows[i] bit j set iff i suppresses j>i
                for (uint32_t widx = t; widx < sl * (SLICE / 32); widx += 1024) {
                    uint32_t i = widx >> 3, wq = widx & 7;
                    float4 bi = box_l[i];
                    float ai = (bi.z - bi.x) * (bi.w - bi.y);
                    uint32_t bits = 0u, jbase = wq * 32u;
                    for (uint32_t q = 0; q < 32u; q++) {
                        uint32_t j = jbase + q;
                        if (j > i && j < sl) {
                            float4 bj = box_l[j];
                            float xx1 = fmaxf(bi.x, bj.x), yy1 = fmaxf(bi.y, bj.y);
                            float xx2 = fminf(bi.z, bj.z), yy2 = fminf(bi.w, bj.w);
                            float inter = fmaxf(xx2 - xx1, 0.f) * fmaxf(yy2 - yy1, 0.f);
                            float aj = (bj.z - bj.x) * (bj.w - bj.y);
                            float un = ai + aj - inter;
                            if (un > 0.f && inter / un > 0.7f) bits |= 1u << q;
                        }
                    }
                    rows[i * (SLICE / 32) + wq] = bits;
                }
                __syncthreads();
                // greedy sweep by wave 0 (pure bit ops)
                if (wid == 0) {
                    uint32_t myw = (lane < SLICE / 32) ? sup[lane] : 0u;
                    uint32_t pk = picks;
                    for (uint32_t i = 0; i < sl && pk < 100u; i++) {
                        uint32_t wv = __shfl(myw, (int)(i >> 5), 64);
                        if (!((wv >> (i & 31)) & 1u)) {
                            if (lane < SLICE / 32) myw |= rows[i * (SLICE / 32) + lane];
                            if (lane == 0) {
                                float4 cb = box_l[i];
                                sel_l[pk] = cb;
                                unsigned long long mkey = k_l[s0 + i];
                                uint32_t n = ~(uint32_t)(mkey & 0xFFFFFFFFull);
                                float off = (float)level_of((int)n) * 1217.0f;
                                float* ob = out + ((size_t)b * 100 + pk) * 4;
                                ob[0] = cb.x - off; ob[1] = cb.y - off;
                                ob[2] = cb.z - off; ob[3] = cb.w - off;
                                uint32_t uu = (uint32_t)(mkey >> 32);
                                uint32_t sb2 = (uu & 0x80000000u) ? (uu ^ 0x80000000u) : ~uu;
                                out[3200 + b * 100 + pk] = __uint_as_float(sb2);
                            }
                            pk++;
                        }
                    }
                    if (lane == 0) picks_sh = pk;
                }
                __syncthreads();
                picks = picks_sh;
            }
        } else {
            // exact serial fallback (not expected with this data)
            unsigned long long last = 0ull;
            bool first = true;
            for (uint32_t done = 0; done < cnt && picks < 100u; done++) {
                unsigned long long lbest = 0ull;
                uint32_t jbest = 0;
                for (int j = t; j < KTOT; j += 1024) {
                    unsigned long long kk = K[j];
                    if (kk != 0ull && chunk_of[(uint32_t)(kk >> 52)] == (unsigned char)m &&
                        (first || kk < last) && kk > lbest) { lbest = kk; jbest = (uint32_t)j; }
                }
                unsigned long long wm = lbest;
#pragma unroll
                for (int o2 = 32; o2 > 0; o2 >>= 1) {
                    unsigned long long oth = __shfl_down(wm, o2, 64);
                    if (oth > wm) wm = oth;
                }
                if (lane == 0) wred[wid] = wm;
                __syncthreads();
                if (t == 0) {
                    unsigned long long mm = wred[0];
                    for (int q = 1; q < 16; q++) if (wred[q] > mm) mm = wred[q];
                    gmax_sh = mm;
                }
                __syncthreads();
                unsigned long long gm = gmax_sh;
                if (gm == 0ull) break;
                if (lbest == gm) jpos_sh = jbest;   // unique owner
                __syncthreads();
                float4 cb = BX[jpos_sh];
                float ca = (cb.z - cb.x) * (cb.w - cb.y);
                bool hit = false;
                for (uint32_t s = (uint32_t)lane; s < picks; s += 64u) {
                    float4 sv = sel_l[s];
                    float xx1 = fmaxf(cb.x, sv.x), yy1 = fmaxf(cb.y, sv.y);
                    float xx2 = fminf(cb.z, sv.z), yy2 = fminf(cb.w, sv.w);
                    float inter = fmaxf(xx2 - xx1, 0.f) * fmaxf(yy2 - yy1, 0.f);
                    float sa = (sv.z - sv.x) * (sv.w - sv.y);
                    float un = ca + sa - inter;
                    hit = hit || (un > 0.f && inter / un > 0.7f);
                }
                bool selq = (__ballot(hit) == 0ull);
                if (selq) {
                    if (t == 0) {
                        sel_l[picks] = cb;
                        uint32_t n = ~(uint32_t)(gm & 0xFFFFFFFFull);
                        float off = (float)level_of((int)n) * 1217.0f;
                        float* ob = out + ((size_t)b * 100 + picks) * 4;
                        ob[0] = cb.x - off; ob[1] = cb.y - off;
                        ob[2] = cb.z - off; ob[3] = cb.w - off;
                        uint32_t uu = (uint32_t)(gm >> 32);
                        uint32_t sb2 = (uu & 0x80000000u) ? (uu ^ 0x80000000u) : ~uu;
                        out[3200 + b * 100 + picks] = __uint_as_float(sb2);
                    }
                    picks++;
                }
                last = gm; first = false;
                __syncthreads();
            }
            if (t == 0) picks_sh = picks;
            __syncthreads();
        }
    }
    // zero-fill unselected output slots
    for (uint32_t i = picks + (uint32_t)t; i < 100u; i += 1024u) {
        float* ob = out + ((size_t)b * 100 + i) * 4;
        ob[0] = 0.f; ob[1] = 0.f; ob[2] = 0.f; ob[3] = 0.f;
        out[3200 + b * 100 + i] = 0.f;
    }
}

extern "C" void kernel_launch(void* const* d_in, const int* in_sizes, int n_in,
                              void* d_out, int out_size, void* d_ws, size_t ws_size,
                              hipStream_t stream) {
    // setup_inputs() order: cls0, box0, cls1, box1, cls2, box2, cls3, box3, cls4, box4, anchors
    const float* cls[5] = { (const float*)d_in[0], (const float*)d_in[2], (const float*)d_in[4],
                            (const float*)d_in[6], (const float*)d_in[8] };
    const float* box[5] = { (const float*)d_in[1], (const float*)d_in[3], (const float*)d_in[5],
                            (const float*)d_in[7], (const float*)d_in[9] };
    const float* anchors = (const float*)d_in[10];
    float* out = (float*)d_out;

    // ---- workspace layout (u32 units). Zero blob first (one memset). ----
    uint32_t* W32 = (uint32_t*)d_ws;
    size_t o = 0;
    uint32_t* hist     = W32 + o; o += (size_t)40 * NBIN;      // 163840
    uint32_t* shist    = W32 + o; o += (size_t)BATCH * NBIN;   // 32768
    uint32_t* keep_cnt = W32 + o; o += 40 * CSTR;              // 640
    uint32_t* cand_cnt = W32 + o; o += 40 * CSTR;              // 640
    size_t zero_n = o;
    int*      binT     = (int*)(W32 + o); o += 64;
    int*      rrem     = (int*)(W32 + o); o += 64;
    uint32_t* keys32   = W32 + o; o += (size_t)ANCTOT;
    uint32_t* keep     = W32 + o; o += (size_t)BATCH * KTOT;
    uint32_t* cand     = W32 + o; o += (size_t)40 * CAP;
    o = (o + 3) & ~(size_t)3;                                  // 16B align
    float4* nbox = (float4*)(W32 + o); o += (size_t)BATCH * KTOT * 4;
    unsigned long long* nkey = (unsigned long long*)(W32 + o); o += (size_t)BATCH * KTOT * 2;

    hipMemsetAsync(d_ws, 0, zero_n * sizeof(uint32_t), stream);
    k_keys<<<(MEMTOT + 1023) / 1024, 1024, 0, stream>>>(cls[0], cls[1], cls[2], cls[3], cls[4],
                                                        keys32, hist);
    k_bins<<<40, 256, 0, stream>>>(hist, binT, rrem);
    k_compact<<<(ANCTOT + 1023) / 1024, 1024, 0, stream>>>(keys32, binT, keep, keep_cnt,
                                                           cand, cand_cnt);
    k_select<<<40, 1024, 0, stream>>>(keys32, cand, cand_cnt, rrem, keep, keep_cnt);
    {
        int tot = BATCH * KTOT;
        k_decode<<<(tot + 255) / 256, 256, 0, stream>>>(box[0], box[1], box[2], box[3], box[4],
                                                        anchors, keys32, keep, nbox, nkey, shist);
    }
    k_scan<<<BATCH, 1024, 0, stream>>>(nkey, nbox, shist, out);
}